// Round 1
// baseline (687.805 us; speedup 1.0000x reference)
//
#include <hip/hip_runtime.h>
#include <cstdint>

#define B_    16
#define N_    128
#define P_    4096
#define M_    65536     // B_*P_
#define DIN   1024
#define DHID  512
#define DGEO  128
#define DEMB  200
#define NODEF 328       // DGEO + DEMB
#define NOBJ  151
#define OUTC  50
#define KGEO  656
#define KGEOP 704       // padded to multiple of 64

typedef __attribute__((ext_vector_type(8))) short bf16x8;
typedef __attribute__((ext_vector_type(4))) float f32x4;

static __device__ __forceinline__ unsigned short f2b(float f) {
  union { float f; unsigned u; } v; v.f = f;
  unsigned r = v.u + 0x7fffu + ((v.u >> 16) & 1u);
  return (unsigned short)(r >> 16);
}
static __device__ __forceinline__ float b2f(unsigned short b) {
  union { unsigned u; float f; } v; v.u = ((unsigned)b) << 16;
  return v.f;
}
static __device__ __forceinline__ unsigned pack2(float a, float b) {
  return (unsigned)f2b(a) | ((unsigned)f2b(b) << 16);
}
static __device__ __forceinline__ void unpack8(uint4 raw, float* x) {
  x[0] = b2f(raw.x & 0xffffu); x[1] = b2f(raw.x >> 16);
  x[2] = b2f(raw.y & 0xffffu); x[3] = b2f(raw.y >> 16);
  x[4] = b2f(raw.z & 0xffffu); x[5] = b2f(raw.z >> 16);
  x[6] = b2f(raw.w & 0xffffu); x[7] = b2f(raw.w >> 16);
}

// ---- weight transpose + bf16 cast: wT[n][k] = w[k][n], zero-padded ----
__global__ void transpose_cvt(const float* __restrict__ w, unsigned short* __restrict__ wT,
                              int K, int Nw, int Kpad, int Npad) {
  int idx = blockIdx.x * blockDim.x + threadIdx.x;
  if (idx >= Npad * Kpad) return;
  int n = idx / Kpad, k = idx - n * Kpad;
  float v = (n < Nw && k < K) ? w[(size_t)k * Nw + n] : 0.f;
  wT[idx] = f2b(v);
}

// ---- per-node features: nodeF[node] = [pos(128), sem(200)] ----
__global__ __launch_bounds__(128)
void node_kernel(const float* __restrict__ box, const float* __restrict__ plog,
                 const float* __restrict__ semw,
                 const float* __restrict__ w1, const float* __restrict__ b1,
                 const float* __restrict__ w2, const float* __restrict__ b2,
                 float* __restrict__ nodeF) {
  const int node = blockIdx.x;          // 0..2047
  const int t = threadIdx.x;            // 0..127 (2 waves)
  __shared__ float sBox[9];
  __shared__ float sH[128];
  __shared__ float sE[NOBJ];
  __shared__ float sRed[4];
  if (t < 9) sBox[t] = box[node * 9 + t];
  float l0 = (t < NOBJ) ? plog[node * NOBJ + t] : -1e30f;
  float l1 = (t + 128 < NOBJ) ? plog[node * NOBJ + t + 128] : -1e30f;
  __syncthreads();
  // pos hidden: relu(box @ w1 + b1)
  float h = b1[t];
#pragma unroll
  for (int i = 0; i < 9; i++) h = fmaf(sBox[i], w1[i * 128 + t], h);
  h = fmaxf(h, 0.f);
  sH[t] = h;
  // softmax max over 151 (2-wave reduce)
  float mx = fmaxf(l0, l1);
#pragma unroll
  for (int off = 32; off >= 1; off >>= 1) mx = fmaxf(mx, __shfl_xor(mx, off));
  if ((t & 63) == 0) sRed[t >> 6] = mx;
  __syncthreads();
  mx = fmaxf(sRed[0], sRed[1]);
  float e0 = (t < NOBJ) ? expf(l0 - mx) : 0.f;
  float e1 = (t + 128 < NOBJ) ? expf(l1 - mx) : 0.f;
  if (t < NOBJ) sE[t] = e0;
  if (t + 128 < NOBJ) sE[t + 128] = e1;
  float sm = e0 + e1;
#pragma unroll
  for (int off = 32; off >= 1; off >>= 1) sm += __shfl_xor(sm, off);
  if ((t & 63) == 0) sRed[2 + (t >> 6)] = sm;
  __syncthreads();
  const float inv = 1.f / (sRed[2] + sRed[3]);
  // pos output dim t
  float pv = b2[t];
  for (int i = 0; i < 128; i++) pv = fmaf(sH[i], w2[i * 128 + t], pv);
  nodeF[(size_t)node * NODEF + t] = pv;
  // sem output dims t and t+128
  float a0 = 0.f, a1 = 0.f;
  const int d1 = (t + 128 < DEMB) ? (t + 128) : 0;
  for (int i = 0; i < NOBJ; i++) {
    float e = sE[i];
    a0 = fmaf(e, semw[i * DEMB + t], a0);
    a1 = fmaf(e, semw[i * DEMB + d1], a1);
  }
  nodeF[(size_t)node * NODEF + 128 + t] = a0 * inv;
  if (t + 128 < DEMB) nodeF[(size_t)node * NODEF + 128 + t + 128] = a1 * inv;
}

// ---- row LayerNorm stats: mu, rsqrt(var+eps) ----
template<int D>
__global__ __launch_bounds__(256)
void stats_kernel(const unsigned short* __restrict__ X, float* __restrict__ st) {
  const int lane = threadIdx.x & 63, wid = threadIdx.x >> 6;
  const size_t row = (size_t)blockIdx.x * 4 + wid;
  const unsigned short* xp = X + row * D + lane * (D / 64);
  float s = 0.f, s2 = 0.f;
#pragma unroll
  for (int c = 0; c < D / 64; c += 8) {
    uint4 raw = *(const uint4*)(xp + c);
    float x[8]; unpack8(raw, x);
#pragma unroll
    for (int q = 0; q < 8; q++) { s += x[q]; s2 = fmaf(x[q], x[q], s2); }
  }
#pragma unroll
  for (int off = 32; off >= 1; off >>= 1) { s += __shfl_xor(s, off); s2 += __shfl_xor(s2, off); }
  if (lane == 0) {
    float mu = s / D;
    float var = s2 / D - mu * mu;
    st[row * 2] = mu;
    st[row * 2 + 1] = rsqrtf(var + 1e-5f);
  }
}

// ---- MFMA GEMM: C[M x 128-block] = transform(A) @ Bt^T, 128x128 tile, BK=64 ----
// MODE 0: A = relu(f32 visual_feat), out bf16 -> fused[:, 0:512]
// MODE 1: A = relu(gathered nodeF), out bf16 -> fused[:, 512:1024]
// MODE 2: A = relu(LN(fused bf16)),  out bf16 -> fused2
// MODE 3: A = relu(LN(fused2 bf16)), out f32  -> logits (cols < 50)
template<int MODE>
__global__ __launch_bounds__(256, 2)
void gemm_kernel(const void* __restrict__ Asrc,
                 const unsigned short* __restrict__ Bt,
                 const float* __restrict__ bias,
                 void* __restrict__ Cdst,
                 int Ktot,
                 const int* __restrict__ pair_idx,
                 const float* __restrict__ nodeF,
                 const float* __restrict__ stats,
                 const float* __restrict__ lng,
                 const float* __restrict__ lnb) {
  __shared__ unsigned short ldsA[128 * 72];
  __shared__ unsigned short ldsB[128 * 72];
  const int tid = threadIdx.x;
  const int lane = tid & 63, wid = tid >> 6;
  const int bm = blockIdx.x, bn = blockIdx.y;
  const int sr = tid >> 1, hh = tid & 1;      // staging: row/col, K-half
  const int growA = bm * 128 + sr;
  const int gcolB = bn * 128 + sr;

  int nS = 0, nO = 0; float mu = 0.f, rs = 0.f;
  if (MODE == 1) {
    int b = growA >> 12;
    int s = pair_idx[2 * growA], o = pair_idx[2 * growA + 1];
    nS = (b << 7) + s; nO = (b << 7) + o;
  }
  if (MODE == 2 || MODE == 3) { mu = stats[2 * growA]; rs = stats[2 * growA + 1]; }

  f32x4 acc[4][4];
#pragma unroll
  for (int m = 0; m < 4; m++)
#pragma unroll
    for (int n = 0; n < 4; n++) acc[m][n] = (f32x4){0.f, 0.f, 0.f, 0.f};

  const int wm = wid >> 1, wn = wid & 1;
  const int kgrp = (lane >> 4) << 3;

  for (int kt = 0; kt < Ktot; kt += 64) {
    const int k0 = kt + hh * 32;
    __syncthreads();
    unsigned short* adst = &ldsA[sr * 72 + hh * 32];
    if (MODE == 0) {
      const float* ap = (const float*)Asrc + (size_t)growA * Ktot + k0;
#pragma unroll
      for (int j8 = 0; j8 < 4; j8++) {
        float4 v0 = *(const float4*)(ap + j8 * 8);
        float4 v1 = *(const float4*)(ap + j8 * 8 + 4);
        uint4 u;
        u.x = pack2(fmaxf(v0.x, 0.f), fmaxf(v0.y, 0.f));
        u.y = pack2(fmaxf(v0.z, 0.f), fmaxf(v0.w, 0.f));
        u.z = pack2(fmaxf(v1.x, 0.f), fmaxf(v1.y, 0.f));
        u.w = pack2(fmaxf(v1.z, 0.f), fmaxf(v1.w, 0.f));
        *(uint4*)(adst + j8 * 8) = u;
      }
    } else if (MODE == 1) {
#pragma unroll
      for (int j8 = 0; j8 < 4; j8++) {
        int k = k0 + j8 * 8;
        float4 v0, v1;
        if (k < NODEF) {
          const float* p = nodeF + (size_t)nS * NODEF + k;
          v0 = *(const float4*)p; v1 = *(const float4*)(p + 4);
        } else if (k < KGEO) {
          const float* p = nodeF + (size_t)nO * NODEF + (k - NODEF);
          v0 = *(const float4*)p; v1 = *(const float4*)(p + 4);
        } else {
          v0 = make_float4(0.f, 0.f, 0.f, 0.f); v1 = v0;
        }
        uint4 u;
        u.x = pack2(fmaxf(v0.x, 0.f), fmaxf(v0.y, 0.f));
        u.y = pack2(fmaxf(v0.z, 0.f), fmaxf(v0.w, 0.f));
        u.z = pack2(fmaxf(v1.x, 0.f), fmaxf(v1.y, 0.f));
        u.w = pack2(fmaxf(v1.z, 0.f), fmaxf(v1.w, 0.f));
        *(uint4*)(adst + j8 * 8) = u;
      }
    } else {
      const unsigned short* ap = (const unsigned short*)Asrc + (size_t)growA * Ktot + k0;
#pragma unroll
      for (int j8 = 0; j8 < 4; j8++) {
        uint4 raw = *(const uint4*)(ap + j8 * 8);
        float x[8]; unpack8(raw, x);
        const float* gp = lng + k0 + j8 * 8;
        const float* tp = lnb + k0 + j8 * 8;
        float4 g0 = *(const float4*)gp, g1 = *(const float4*)(gp + 4);
        float4 t0 = *(const float4*)tp, t1 = *(const float4*)(tp + 4);
        float y0 = fmaxf(fmaf((x[0] - mu) * rs, g0.x, t0.x), 0.f);
        float y1 = fmaxf(fmaf((x[1] - mu) * rs, g0.y, t0.y), 0.f);
        float y2 = fmaxf(fmaf((x[2] - mu) * rs, g0.z, t0.z), 0.f);
        float y3 = fmaxf(fmaf((x[3] - mu) * rs, g0.w, t0.w), 0.f);
        float y4 = fmaxf(fmaf((x[4] - mu) * rs, g1.x, t1.x), 0.f);
        float y5 = fmaxf(fmaf((x[5] - mu) * rs, g1.y, t1.y), 0.f);
        float y6 = fmaxf(fmaf((x[6] - mu) * rs, g1.z, t1.z), 0.f);
        float y7 = fmaxf(fmaf((x[7] - mu) * rs, g1.w, t1.w), 0.f);
        uint4 u;
        u.x = pack2(y0, y1); u.y = pack2(y2, y3);
        u.z = pack2(y4, y5); u.w = pack2(y6, y7);
        *(uint4*)(adst + j8 * 8) = u;
      }
    }
    { // stage Bt (already bf16, row-major [col][k])
      const unsigned short* bp = Bt + (size_t)gcolB * Ktot + k0;
      unsigned short* bdst = &ldsB[sr * 72 + hh * 32];
#pragma unroll
      for (int j8 = 0; j8 < 4; j8++)
        *(uint4*)(bdst + j8 * 8) = *(const uint4*)(bp + j8 * 8);
    }
    __syncthreads();
#pragma unroll
    for (int kk = 0; kk < 64; kk += 32) {
      bf16x8 af[4], bfr[4];
#pragma unroll
      for (int m = 0; m < 4; m++)
        af[m] = *(const bf16x8*)&ldsA[(wm * 64 + m * 16 + (lane & 15)) * 72 + kk + kgrp];
#pragma unroll
      for (int n = 0; n < 4; n++)
        bfr[n] = *(const bf16x8*)&ldsB[(wn * 64 + n * 16 + (lane & 15)) * 72 + kk + kgrp];
#pragma unroll
      for (int m = 0; m < 4; m++)
#pragma unroll
        for (int n = 0; n < 4; n++)
          acc[m][n] = __builtin_amdgcn_mfma_f32_16x16x32_bf16(af[m], bfr[n], acc[m][n], 0, 0, 0);
    }
  }
  // epilogue: C/D layout col=lane&15, row=(lane>>4)*4+i
  const int rb = bm * 128 + wm * 64 + ((lane >> 4) << 2);
  const int cb = bn * 128 + wn * 64 + (lane & 15);
#pragma unroll
  for (int n = 0; n < 4; n++) {
    const int col = cb + n * 16;
    float bv = 0.f;
    if (MODE == 3) { if (col < OUTC) bv = bias[col]; }
    else bv = bias[col];
#pragma unroll
    for (int m = 0; m < 4; m++)
#pragma unroll
      for (int i = 0; i < 4; i++) {
        const int row = rb + m * 16 + i;
        const float v = acc[m][n][i] + bv;
        if (MODE == 0) ((unsigned short*)Cdst)[(size_t)row * 1024 + col] = f2b(v);
        else if (MODE == 1) ((unsigned short*)Cdst)[(size_t)row * 1024 + 512 + col] = f2b(v);
        else if (MODE == 2) ((unsigned short*)Cdst)[(size_t)row * 512 + col] = f2b(v);
        else if (col < OUTC) ((float*)Cdst)[(size_t)row * OUTC + col] = v;
      }
  }
}

// ---- rowmax -> sigmoid -> last-wins scatter via atomicMax((p+1)<<32 | bits) ----
__global__ void score_kernel(const float* __restrict__ logits, const int* __restrict__ pidx,
                             unsigned long long* __restrict__ scat) {
  int row = blockIdx.x * blockDim.x + threadIdx.x;
  if (row >= M_) return;
  const float* lp = logits + (size_t)row * OUTC;
  float mx = lp[0];
#pragma unroll
  for (int j = 0; j < OUTC; j += 2) {
    float2 v = *(const float2*)(lp + j);
    mx = fmaxf(mx, fmaxf(v.x, v.y));
  }
  float sc = 1.f / (1.f + expf(-mx));
  int b = row >> 12, p = row & 4095;
  int s = pidx[2 * row], o = pidx[2 * row + 1];
  unsigned long long key = (((unsigned long long)(p + 1)) << 32) | (unsigned long long)__float_as_uint(sc);
  atomicMax(&scat[((size_t)(b * N_ + s) << 7) + o], key);
}

__global__ void relmat_kernel(const unsigned long long* __restrict__ scat, float* __restrict__ out) {
  int i = blockIdx.x * blockDim.x + threadIdx.x;
  if (i >= B_ * N_ * N_) return;
  unsigned long long v = scat[i];
  out[i] = v ? __uint_as_float((unsigned)(v & 0xffffffffu)) : 0.f;
}

extern "C" void kernel_launch(void* const* d_in, const int* in_sizes, int n_in,
                              void* d_out, int out_size, void* d_ws, size_t ws_size,
                              hipStream_t stream) {
  const float* visual_feat = (const float*)d_in[0];
  const float* box_info    = (const float*)d_in[1];
  const float* pred_logits = (const float*)d_in[2];
  const int*   pair_idx    = (const int*)d_in[3];
  const float* obj_sem_w   = (const float*)d_in[4];
  const float* pos_w1 = (const float*)d_in[5];
  const float* pos_b1 = (const float*)d_in[6];
  const float* pos_w2 = (const float*)d_in[7];
  const float* pos_b2 = (const float*)d_in[8];
  const float* vis_w  = (const float*)d_in[9];
  const float* vis_b  = (const float*)d_in[10];
  const float* geo_w  = (const float*)d_in[11];
  const float* geo_b  = (const float*)d_in[12];
  const float* fus_g  = (const float*)d_in[13];
  const float* fus_bt = (const float*)d_in[14];
  const float* fus_w  = (const float*)d_in[15];
  const float* fus_b  = (const float*)d_in[16];
  const float* cls_g  = (const float*)d_in[17];
  const float* cls_bt = (const float*)d_in[18];
  const float* cls_w  = (const float*)d_in[19];
  const float* cls_b  = (const float*)d_in[20];

  char* ws = (char*)d_ws;
  size_t off = 0;
  auto alloc = [&](size_t bytes) { char* p = ws + off; off += (bytes + 255) & ~(size_t)255; return p; };
  unsigned short* fused  = (unsigned short*)alloc((size_t)M_ * 1024 * 2);
  unsigned short* fused2 = (unsigned short*)alloc((size_t)M_ * 512 * 2);
  float* nodeF = (float*)alloc((size_t)B_ * N_ * NODEF * 4);
  unsigned short* wT_vis = (unsigned short*)alloc((size_t)512 * 1024 * 2);
  unsigned short* wT_geo = (unsigned short*)alloc((size_t)512 * KGEOP * 2);
  unsigned short* wT_fus = (unsigned short*)alloc((size_t)512 * 1024 * 2);
  unsigned short* wT_cls = (unsigned short*)alloc((size_t)128 * 512 * 2);
  float* stats1 = (float*)alloc((size_t)M_ * 2 * 4);
  float* stats2 = (float*)alloc((size_t)M_ * 2 * 4);
  unsigned long long* scat = (unsigned long long*)alloc((size_t)B_ * N_ * N_ * 8);

  float* out_logits = (float*)d_out;
  float* out_rel = out_logits + (size_t)M_ * OUTC;

  transpose_cvt<<<dim3((512 * 1024 + 255) / 256), 256, 0, stream>>>(vis_w, wT_vis, 1024, 512, 1024, 512);
  transpose_cvt<<<dim3((512 * KGEOP + 255) / 256), 256, 0, stream>>>(geo_w, wT_geo, KGEO, 512, KGEOP, 512);
  transpose_cvt<<<dim3((512 * 1024 + 255) / 256), 256, 0, stream>>>(fus_w, wT_fus, 1024, 512, 1024, 512);
  transpose_cvt<<<dim3((128 * 512 + 255) / 256), 256, 0, stream>>>(cls_w, wT_cls, 512, OUTC, 512, 128);
  node_kernel<<<dim3(B_ * N_), 128, 0, stream>>>(box_info, pred_logits, obj_sem_w,
                                                 pos_w1, pos_b1, pos_w2, pos_b2, nodeF);
  gemm_kernel<0><<<dim3(512, 4), 256, 0, stream>>>(visual_feat, wT_vis, vis_b, fused, 1024,
                                                   nullptr, nullptr, nullptr, nullptr, nullptr);
  gemm_kernel<1><<<dim3(512, 4), 256, 0, stream>>>(nullptr, wT_geo, geo_b, fused, KGEOP,
                                                   pair_idx, nodeF, nullptr, nullptr, nullptr);
  stats_kernel<1024><<<dim3(M_ / 4), 256, 0, stream>>>(fused, stats1);
  gemm_kernel<2><<<dim3(512, 4), 256, 0, stream>>>(fused, wT_fus, fus_b, fused2, 1024,
                                                   nullptr, nullptr, stats1, fus_g, fus_bt);
  stats_kernel<512><<<dim3(M_ / 4), 256, 0, stream>>>(fused2, stats2);
  gemm_kernel<3><<<dim3(512, 1), 256, 0, stream>>>(fused2, wT_cls, cls_b, out_logits, 512,
                                                   nullptr, nullptr, stats2, cls_g, cls_bt);
  hipMemsetAsync(scat, 0, (size_t)B_ * N_ * N_ * 8, stream);
  score_kernel<<<dim3(M_ / 256), 256, 0, stream>>>(out_logits, pair_idx, scat);
  relmat_kernel<<<dim3((B_ * N_ * N_) / 256), 256, 0, stream>>>(scat, out_rel);
}

// Round 2
// 563.158 us; speedup vs baseline: 1.2213x; 1.2213x over previous
//
#include <hip/hip_runtime.h>
#include <cstdint>

#define B_    16
#define N_    128
#define P_    4096
#define M_    65536     // B_*P_
#define DIN   1024
#define DHID  512
#define DGEO  128
#define DEMB  200
#define NODEF 328       // DGEO + DEMB
#define NOBJ  151
#define OUTC  50
#define KGEO  656
#define KGEOP 704       // padded to multiple of 64

typedef __attribute__((ext_vector_type(8))) short bf16x8;
typedef __attribute__((ext_vector_type(4))) float f32x4;

typedef __attribute__((address_space(3))) unsigned char lds_u8;
typedef __attribute__((address_space(1))) unsigned char glb_u8;

static __device__ __forceinline__ void async_copy16(const void* g, void* l) {
  __builtin_amdgcn_global_load_lds((const glb_u8*)g, (lds_u8*)l, 16, 0, 0);
}

static __device__ __forceinline__ unsigned short f2b(float f) {
  union { float f; unsigned u; } v; v.f = f;
  unsigned r = v.u + 0x7fffu + ((v.u >> 16) & 1u);
  return (unsigned short)(r >> 16);
}
static __device__ __forceinline__ float b2f(unsigned short b) {
  union { unsigned u; float f; } v; v.u = ((unsigned)b) << 16;
  return v.f;
}
static __device__ __forceinline__ unsigned pack2(float a, float b) {
  return (unsigned)f2b(a) | ((unsigned)f2b(b) << 16);
}
static __device__ __forceinline__ void unpack8(uint4 raw, float* x) {
  x[0] = b2f(raw.x & 0xffffu); x[1] = b2f(raw.x >> 16);
  x[2] = b2f(raw.y & 0xffffu); x[3] = b2f(raw.y >> 16);
  x[4] = b2f(raw.z & 0xffffu); x[5] = b2f(raw.z >> 16);
  x[6] = b2f(raw.w & 0xffffu); x[7] = b2f(raw.w >> 16);
}

// ---- weight transpose + bf16 cast: wT[n][k] = w[k][n], zero-padded ----
__global__ void transpose_cvt(const float* __restrict__ w, unsigned short* __restrict__ wT,
                              int K, int Nw, int Kpad, int Npad) {
  int idx = blockIdx.x * blockDim.x + threadIdx.x;
  if (idx >= Npad * Kpad) return;
  int n = idx / Kpad, k = idx - n * Kpad;
  float v = (n < Nw && k < K) ? w[(size_t)k * Nw + n] : 0.f;
  wT[idx] = f2b(v);
}

// ---- per-node features (relu'd, bf16): nodeFb[node] = [relu(pos)(128), relu(sem)(200)] ----
__global__ __launch_bounds__(128)
void node_kernel(const float* __restrict__ box, const float* __restrict__ plog,
                 const float* __restrict__ semw,
                 const float* __restrict__ w1, const float* __restrict__ b1,
                 const float* __restrict__ w2, const float* __restrict__ b2,
                 unsigned short* __restrict__ nodeFb) {
  const int node = blockIdx.x;          // 0..2047
  const int t = threadIdx.x;            // 0..127 (2 waves)
  __shared__ float sBox[9];
  __shared__ float sH[128];
  __shared__ float sE[NOBJ];
  __shared__ float sRed[4];
  if (t < 9) sBox[t] = box[node * 9 + t];
  float l0 = (t < NOBJ) ? plog[node * NOBJ + t] : -1e30f;
  float l1 = (t + 128 < NOBJ) ? plog[node * NOBJ + t + 128] : -1e30f;
  __syncthreads();
  float h = b1[t];
#pragma unroll
  for (int i = 0; i < 9; i++) h = fmaf(sBox[i], w1[i * 128 + t], h);
  h = fmaxf(h, 0.f);
  sH[t] = h;
  float mx = fmaxf(l0, l1);
#pragma unroll
  for (int off = 32; off >= 1; off >>= 1) mx = fmaxf(mx, __shfl_xor(mx, off));
  if ((t & 63) == 0) sRed[t >> 6] = mx;
  __syncthreads();
  mx = fmaxf(sRed[0], sRed[1]);
  float e0 = (t < NOBJ) ? expf(l0 - mx) : 0.f;
  float e1 = (t + 128 < NOBJ) ? expf(l1 - mx) : 0.f;
  if (t < NOBJ) sE[t] = e0;
  if (t + 128 < NOBJ) sE[t + 128] = e1;
  float sm = e0 + e1;
#pragma unroll
  for (int off = 32; off >= 1; off >>= 1) sm += __shfl_xor(sm, off);
  if ((t & 63) == 0) sRed[2 + (t >> 6)] = sm;
  __syncthreads();
  const float inv = 1.f / (sRed[2] + sRed[3]);
  float pv = b2[t];
  for (int i = 0; i < 128; i++) pv = fmaf(sH[i], w2[i * 128 + t], pv);
  nodeFb[(size_t)node * NODEF + t] = f2b(fmaxf(pv, 0.f));
  float a0 = 0.f, a1 = 0.f;
  const int d1 = (t + 128 < DEMB) ? (t + 128) : 0;
  for (int i = 0; i < NOBJ; i++) {
    float e = sE[i];
    a0 = fmaf(e, semw[i * DEMB + t], a0);
    a1 = fmaf(e, semw[i * DEMB + d1], a1);
  }
  nodeFb[(size_t)node * NODEF + 128 + t] = f2b(fmaxf(a0 * inv, 0.f));
  if (t + 128 < DEMB) nodeFb[(size_t)node * NODEF + 128 + t + 128] = f2b(fmaxf(a1 * inv, 0.f));
}

// ---- gather pair rows: pairA[row][704] = [nodeFb[s](328), nodeFb[o](328), 0(48)] ----
__global__ __launch_bounds__(256)
void gather_kernel(const int* __restrict__ pidx, const unsigned short* __restrict__ nodeFb,
                   unsigned short* __restrict__ pairA) {
  const int lane = threadIdx.x & 63, wv = threadIdx.x >> 6;
  const int row = blockIdx.x * 4 + wv;        // wave per row
  const int b = row >> 12;
  const int s = pidx[2 * row], o = pidx[2 * row + 1];
  const uint4* ps = (const uint4*)(nodeFb + (size_t)((b << 7) + s) * NODEF);
  const uint4* po = (const uint4*)(nodeFb + (size_t)((b << 7) + o) * NODEF);
  uint4* dst = (uint4*)(pairA + (size_t)row * KGEOP);
  const uint4 z = make_uint4(0, 0, 0, 0);
  // 88 chunks of 8 shorts: 0..40 subj, 41..81 obj, 82..87 zero
  int c = lane;
  dst[c] = (c < 41) ? ps[c] : (c < 82) ? po[c - 41] : z;
  if (lane < 24) {
    c = lane + 64;
    dst[c] = (c < 82) ? po[c - 41] : z;
  }
}

// ---- relu + f32->bf16 cast (vectorized, grid-stride) ----
__global__ __launch_bounds__(256)
void relu_cast_kernel(const float* __restrict__ in, unsigned short* __restrict__ out, int n8) {
  for (int i = blockIdx.x * blockDim.x + threadIdx.x; i < n8; i += gridDim.x * blockDim.x) {
    float4 v0 = ((const float4*)in)[2 * i];
    float4 v1 = ((const float4*)in)[2 * i + 1];
    uint4 u;
    u.x = pack2(fmaxf(v0.x, 0.f), fmaxf(v0.y, 0.f));
    u.y = pack2(fmaxf(v0.z, 0.f), fmaxf(v0.w, 0.f));
    u.z = pack2(fmaxf(v1.x, 0.f), fmaxf(v1.y, 0.f));
    u.w = pack2(fmaxf(v1.z, 0.f), fmaxf(v1.w, 0.f));
    ((uint4*)out)[i] = u;
  }
}

// ---- fused LayerNorm + ReLU, in place, wave per row ----
template<int D>
__global__ __launch_bounds__(256)
void ln_relu_kernel(unsigned short* __restrict__ X,
                    const float* __restrict__ g, const float* __restrict__ bta) {
  constexpr int C = D / 64;                    // elems per lane (16 or 8)
  const int lane = threadIdx.x & 63, wv = threadIdx.x >> 6;
  const size_t row = (size_t)blockIdx.x * 4 + wv;
  unsigned short* xp = X + row * D + lane * C;
  float x[C];
#pragma unroll
  for (int c = 0; c < C; c += 8) {
    uint4 raw = *(const uint4*)(xp + c);
    unpack8(raw, x + c);
  }
  float s = 0.f, s2 = 0.f;
#pragma unroll
  for (int q = 0; q < C; q++) { s += x[q]; s2 = fmaf(x[q], x[q], s2); }
#pragma unroll
  for (int off = 32; off >= 1; off >>= 1) { s += __shfl_xor(s, off); s2 += __shfl_xor(s2, off); }
  const float mu = s / D;
  const float rs = rsqrtf(s2 / D - mu * mu + 1e-5f);
  const float* gp = g + lane * C;
  const float* bp = bta + lane * C;
#pragma unroll
  for (int c = 0; c < C; c += 8) {
    float4 g0 = *(const float4*)(gp + c), g1 = *(const float4*)(gp + c + 4);
    float4 t0 = *(const float4*)(bp + c), t1 = *(const float4*)(bp + c + 4);
    float y0 = fmaxf(fmaf((x[c + 0] - mu) * rs, g0.x, t0.x), 0.f);
    float y1 = fmaxf(fmaf((x[c + 1] - mu) * rs, g0.y, t0.y), 0.f);
    float y2 = fmaxf(fmaf((x[c + 2] - mu) * rs, g0.z, t0.z), 0.f);
    float y3 = fmaxf(fmaf((x[c + 3] - mu) * rs, g0.w, t0.w), 0.f);
    float y4 = fmaxf(fmaf((x[c + 4] - mu) * rs, g1.x, t1.x), 0.f);
    float y5 = fmaxf(fmaf((x[c + 5] - mu) * rs, g1.y, t1.y), 0.f);
    float y6 = fmaxf(fmaf((x[c + 6] - mu) * rs, g1.z, t1.z), 0.f);
    float y7 = fmaxf(fmaf((x[c + 7] - mu) * rs, g1.w, t1.w), 0.f);
    uint4 u;
    u.x = pack2(y0, y1); u.y = pack2(y2, y3);
    u.z = pack2(y4, y5); u.w = pack2(y6, y7);
    *(uint4*)(xp + c) = u;
  }
}

// ---- pure-bf16 MFMA GEMM, m97 structure: 128x128 tile, BK=64, global_load_lds w16 ----
// OUTM 0: bf16 out at C[row*ldc + ccol0 + col]
// OUTM 1: f32 out, cols < OUTC, C[row*OUTC + col]
template<int OUTM>
__global__ __launch_bounds__(256)
void gemm_bf16(const unsigned short* __restrict__ A, int lda,
               const unsigned short* __restrict__ Bt,
               const float* __restrict__ bias,
               void* __restrict__ C, int ldc, int ccol0,
               int Ktot, int NBN) {
  __shared__ unsigned short ldsA[128 * 64];
  __shared__ unsigned short ldsB[128 * 64];
  const int tid = threadIdx.x;
  const int lane = tid & 63, wid = tid >> 6;
  // bijective XCD swizzle (nwg % 8 == 0 for all our grids)
  const int nwg = gridDim.x;
  const int cpx = nwg >> 3;
  const int swz = (blockIdx.x & 7) * cpx + (blockIdx.x >> 3);
  const int bm = swz / NBN, bn = swz - bm * NBN;

  // staging: each wave covers rows [wid*32, wid*32+32) via 4 instrs of 8 rows
  const int srow = wid * 32 + (lane >> 3);
  const int skof = (lane & 7) * 8;
  const unsigned short* ag = A + (size_t)(bm * 128 + srow) * lda + skof;
  const unsigned short* bg = Bt + (size_t)(bn * 128 + srow) * Ktot + skof;

  f32x4 acc[4][4];
#pragma unroll
  for (int m = 0; m < 4; m++)
#pragma unroll
    for (int n = 0; n < 4; n++) acc[m][n] = (f32x4){0.f, 0.f, 0.f, 0.f};

  const int wm = wid >> 1, wn = wid & 1;
  const int frow = lane & 15;
  const int kgrp = (lane >> 4) << 3;

  for (int kt = 0; kt < Ktot; kt += 64) {
#pragma unroll
    for (int i = 0; i < 4; i++) {
      async_copy16(ag + (size_t)i * 8 * lda + kt, &ldsA[wid * 2048 + i * 512]);
      async_copy16(bg + (size_t)i * 8 * Ktot + kt, &ldsB[wid * 2048 + i * 512]);
    }
    __syncthreads();
#pragma unroll
    for (int kk = 0; kk < 64; kk += 32) {
      bf16x8 af[4], bfr[4];
#pragma unroll
      for (int m = 0; m < 4; m++)
        af[m] = *(const bf16x8*)&ldsA[(wm * 64 + m * 16 + frow) * 64 + kk + kgrp];
#pragma unroll
      for (int n = 0; n < 4; n++)
        bfr[n] = *(const bf16x8*)&ldsB[(wn * 64 + n * 16 + frow) * 64 + kk + kgrp];
#pragma unroll
      for (int m = 0; m < 4; m++)
#pragma unroll
        for (int n = 0; n < 4; n++)
          acc[m][n] = __builtin_amdgcn_mfma_f32_16x16x32_bf16(af[m], bfr[n], acc[m][n], 0, 0, 0);
    }
    __syncthreads();
  }
  // epilogue: C/D layout col=lane&15, row=(lane>>4)*4+i
  const int rb = bm * 128 + wm * 64 + ((lane >> 4) << 2);
  const int cbl = wn * 64 + frow;
#pragma unroll
  for (int n = 0; n < 4; n++) {
    const int col = bn * 128 + cbl + n * 16;
    float bv = 0.f;
    if (OUTM == 1) { if (col < OUTC) bv = bias[col]; }
    else bv = bias[col];
#pragma unroll
    for (int m = 0; m < 4; m++)
#pragma unroll
      for (int i = 0; i < 4; i++) {
        const int row = rb + m * 16 + i;
        const float v = acc[m][n][i] + bv;
        if (OUTM == 0) ((unsigned short*)C)[(size_t)row * ldc + ccol0 + col] = f2b(v);
        else if (col < OUTC) ((float*)C)[(size_t)row * OUTC + col] = v;
      }
  }
}

// ---- rowmax -> sigmoid -> last-wins scatter via atomicMax((p+1)<<32 | bits) ----
__global__ void score_kernel(const float* __restrict__ logits, const int* __restrict__ pidx,
                             unsigned long long* __restrict__ scat) {
  int row = blockIdx.x * blockDim.x + threadIdx.x;
  if (row >= M_) return;
  const float* lp = logits + (size_t)row * OUTC;
  float mx = lp[0];
#pragma unroll
  for (int j = 0; j < OUTC; j += 2) {
    float2 v = *(const float2*)(lp + j);
    mx = fmaxf(mx, fmaxf(v.x, v.y));
  }
  float sc = 1.f / (1.f + expf(-mx));
  int b = row >> 12, p = row & 4095;
  int s = pidx[2 * row], o = pidx[2 * row + 1];
  unsigned long long key = (((unsigned long long)(p + 1)) << 32) | (unsigned long long)__float_as_uint(sc);
  atomicMax(&scat[((size_t)(b * N_ + s) << 7) + o], key);
}

__global__ void relmat_kernel(const unsigned long long* __restrict__ scat, float* __restrict__ out) {
  int i = blockIdx.x * blockDim.x + threadIdx.x;
  if (i >= B_ * N_ * N_) return;
  unsigned long long v = scat[i];
  out[i] = v ? __uint_as_float((unsigned)(v & 0xffffffffu)) : 0.f;
}

extern "C" void kernel_launch(void* const* d_in, const int* in_sizes, int n_in,
                              void* d_out, int out_size, void* d_ws, size_t ws_size,
                              hipStream_t stream) {
  const float* visual_feat = (const float*)d_in[0];
  const float* box_info    = (const float*)d_in[1];
  const float* pred_logits = (const float*)d_in[2];
  const int*   pair_idx    = (const int*)d_in[3];
  const float* obj_sem_w   = (const float*)d_in[4];
  const float* pos_w1 = (const float*)d_in[5];
  const float* pos_b1 = (const float*)d_in[6];
  const float* pos_w2 = (const float*)d_in[7];
  const float* pos_b2 = (const float*)d_in[8];
  const float* vis_w  = (const float*)d_in[9];
  const float* vis_b  = (const float*)d_in[10];
  const float* geo_w  = (const float*)d_in[11];
  const float* geo_b  = (const float*)d_in[12];
  const float* fus_g  = (const float*)d_in[13];
  const float* fus_bt = (const float*)d_in[14];
  const float* fus_w  = (const float*)d_in[15];
  const float* fus_b  = (const float*)d_in[16];
  const float* cls_g  = (const float*)d_in[17];
  const float* cls_bt = (const float*)d_in[18];
  const float* cls_w  = (const float*)d_in[19];
  const float* cls_b  = (const float*)d_in[20];

  char* ws = (char*)d_ws;
  size_t off = 0;
  auto alloc = [&](size_t bytes) { char* p = ws + off; off += (bytes + 255) & ~(size_t)255; return p; };
  unsigned short* fused = (unsigned short*)alloc((size_t)M_ * 1024 * 2);      // 134 MB
  unsigned short* R1    = (unsigned short*)alloc((size_t)M_ * 1024 * 2);      // 134 MB: pairA -> visA -> fused2
  unsigned short* nodeFb = (unsigned short*)alloc((size_t)B_ * N_ * NODEF * 2);
  unsigned short* wT_vis = (unsigned short*)alloc((size_t)512 * 1024 * 2);
  unsigned short* wT_geo = (unsigned short*)alloc((size_t)512 * KGEOP * 2);
  unsigned short* wT_fus = (unsigned short*)alloc((size_t)512 * 1024 * 2);
  unsigned short* wT_cls = (unsigned short*)alloc((size_t)128 * 512 * 2);
  unsigned long long* scat = (unsigned long long*)alloc((size_t)B_ * N_ * N_ * 8);

  unsigned short* pairA  = R1;      // [M][704]
  unsigned short* visA   = R1;      // [M][1024] (after geo GEMM)
  unsigned short* fused2 = R1;      // [M][512]  (after vis GEMM)

  float* out_logits = (float*)d_out;
  float* out_rel = out_logits + (size_t)M_ * OUTC;

  transpose_cvt<<<dim3((512 * 1024 + 255) / 256), 256, 0, stream>>>(vis_w, wT_vis, 1024, 512, 1024, 512);
  transpose_cvt<<<dim3((512 * KGEOP + 255) / 256), 256, 0, stream>>>(geo_w, wT_geo, KGEO, 512, KGEOP, 512);
  transpose_cvt<<<dim3((512 * 1024 + 255) / 256), 256, 0, stream>>>(fus_w, wT_fus, 1024, 512, 1024, 512);
  transpose_cvt<<<dim3((128 * 512 + 255) / 256), 256, 0, stream>>>(cls_w, wT_cls, 512, OUTC, 512, 128);
  node_kernel<<<dim3(B_ * N_), 128, 0, stream>>>(box_info, pred_logits, obj_sem_w,
                                                 pos_w1, pos_b1, pos_w2, pos_b2, nodeFb);
  gather_kernel<<<dim3(M_ / 4), 256, 0, stream>>>(pair_idx, nodeFb, pairA);
  gemm_bf16<0><<<dim3(512 * 4), 256, 0, stream>>>(pairA, KGEOP, wT_geo, geo_b,
                                                  fused, 1024, 512, KGEOP, 4);
  relu_cast_kernel<<<dim3(2048), 256, 0, stream>>>(visual_feat, visA, M_ * 1024 / 8);
  gemm_bf16<0><<<dim3(512 * 4), 256, 0, stream>>>(visA, 1024, wT_vis, vis_b,
                                                  fused, 1024, 0, 1024, 4);
  ln_relu_kernel<1024><<<dim3(M_ / 4), 256, 0, stream>>>(fused, fus_g, fus_bt);
  gemm_bf16<0><<<dim3(512 * 4), 256, 0, stream>>>(fused, 1024, wT_fus, fus_b,
                                                  fused2, 512, 0, 1024, 4);
  ln_relu_kernel<512><<<dim3(M_ / 4), 256, 0, stream>>>(fused2, cls_g, cls_bt);
  gemm_bf16<1><<<dim3(512), 256, 0, stream>>>(fused2, 512, wT_cls, cls_b,
                                              out_logits, OUTC, 0, 512, 1);
  hipMemsetAsync(scat, 0, (size_t)B_ * N_ * N_ * 8, stream);
  score_kernel<<<dim3(M_ / 256), 256, 0, stream>>>(out_logits, pair_idx, scat);
  relmat_kernel<<<dim3((B_ * N_ * N_) / 256), 256, 0, stream>>>(scat, out_rel);
}

// Round 4
// 495.354 us; speedup vs baseline: 1.3885x; 1.1369x over previous
//
#include <hip/hip_runtime.h>
#include <cstdint>

#define B_    16
#define N_    128
#define P_    4096
#define M_    65536     // B_*P_
#define DIN   1024
#define DHID  512
#define DGEO  128
#define DEMB  200
#define NODEF 328       // DGEO + DEMB
#define NOBJ  151
#define OUTC  50
#define KGEO  656
#define KGEOP 704       // padded to multiple of 64

typedef __attribute__((ext_vector_type(8))) short bf16x8;
typedef __attribute__((ext_vector_type(4))) float f32x4;

typedef __attribute__((address_space(3))) unsigned char lds_u8;
typedef __attribute__((address_space(1))) unsigned char glb_u8;

static __device__ __forceinline__ void async_copy16(const void* g, void* l) {
  __builtin_amdgcn_global_load_lds((const glb_u8*)g, (lds_u8*)l, 16, 0, 0);
}

static __device__ __forceinline__ unsigned short f2b(float f) {
  union { float f; unsigned u; } v; v.f = f;
  unsigned r = v.u + 0x7fffu + ((v.u >> 16) & 1u);
  return (unsigned short)(r >> 16);
}
static __device__ __forceinline__ float b2f(unsigned short b) {
  union { unsigned u; float f; } v; v.u = ((unsigned)b) << 16;
  return v.f;
}
static __device__ __forceinline__ unsigned pack2(float a, float b) {
  return (unsigned)f2b(a) | ((unsigned)f2b(b) << 16);
}
static __device__ __forceinline__ void unpack8(uint4 raw, float* x) {
  x[0] = b2f(raw.x & 0xffffu); x[1] = b2f(raw.x >> 16);
  x[2] = b2f(raw.y & 0xffffu); x[3] = b2f(raw.y >> 16);
  x[4] = b2f(raw.z & 0xffffu); x[5] = b2f(raw.z >> 16);
  x[6] = b2f(raw.w & 0xffffu); x[7] = b2f(raw.w >> 16);
}

// ---- fast zero fill (replaces 157us rocclr fillBuffer) ----
__global__ __launch_bounds__(256)
void zero_kernel(uint4* __restrict__ p) {
  p[blockIdx.x * 256 + threadIdx.x] = make_uint4(0, 0, 0, 0);
}

// ---- weight transpose + bf16 cast: wT[n][k] = w[k][n], zero-padded ----
__global__ void transpose_cvt(const float* __restrict__ w, unsigned short* __restrict__ wT,
                              int K, int Nw, int Kpad, int Npad) {
  int idx = blockIdx.x * blockDim.x + threadIdx.x;
  if (idx >= Npad * Kpad) return;
  int n = idx / Kpad, k = idx - n * Kpad;
  float v = (n < Nw && k < K) ? w[(size_t)k * Nw + n] : 0.f;
  wT[idx] = f2b(v);
}

// ---- per-node features (relu'd, bf16): nodeFb[node] = [relu(pos)(128), relu(sem)(200)] ----
__global__ __launch_bounds__(128)
void node_kernel(const float* __restrict__ box, const float* __restrict__ plog,
                 const float* __restrict__ semw,
                 const float* __restrict__ w1, const float* __restrict__ b1,
                 const float* __restrict__ w2, const float* __restrict__ b2,
                 unsigned short* __restrict__ nodeFb) {
  const int node = blockIdx.x;          // 0..2047
  const int t = threadIdx.x;            // 0..127 (2 waves)
  __shared__ float sBox[9];
  __shared__ float sH[128];
  __shared__ float sE[NOBJ];
  __shared__ float sRed[4];
  if (t < 9) sBox[t] = box[node * 9 + t];
  float l0 = (t < NOBJ) ? plog[node * NOBJ + t] : -1e30f;
  float l1 = (t + 128 < NOBJ) ? plog[node * NOBJ + t + 128] : -1e30f;
  __syncthreads();
  float h = b1[t];
#pragma unroll
  for (int i = 0; i < 9; i++) h = fmaf(sBox[i], w1[i * 128 + t], h);
  h = fmaxf(h, 0.f);
  sH[t] = h;
  float mx = fmaxf(l0, l1);
#pragma unroll
  for (int off = 32; off >= 1; off >>= 1) mx = fmaxf(mx, __shfl_xor(mx, off));
  if ((t & 63) == 0) sRed[t >> 6] = mx;
  __syncthreads();
  mx = fmaxf(sRed[0], sRed[1]);
  float e0 = (t < NOBJ) ? expf(l0 - mx) : 0.f;
  float e1 = (t + 128 < NOBJ) ? expf(l1 - mx) : 0.f;
  if (t < NOBJ) sE[t] = e0;
  if (t + 128 < NOBJ) sE[t + 128] = e1;
  float sm = e0 + e1;
#pragma unroll
  for (int off = 32; off >= 1; off >>= 1) sm += __shfl_xor(sm, off);
  if ((t & 63) == 0) sRed[2 + (t >> 6)] = sm;
  __syncthreads();
  const float inv = 1.f / (sRed[2] + sRed[3]);
  float pv = b2[t];
  for (int i = 0; i < 128; i++) pv = fmaf(sH[i], w2[i * 128 + t], pv);
  nodeFb[(size_t)node * NODEF + t] = f2b(fmaxf(pv, 0.f));
  float a0 = 0.f, a1 = 0.f;
  const int d1 = (t + 128 < DEMB) ? (t + 128) : 0;
  for (int i = 0; i < NOBJ; i++) {
    float e = sE[i];
    a0 = fmaf(e, semw[i * DEMB + t], a0);
    a1 = fmaf(e, semw[i * DEMB + d1], a1);
  }
  nodeFb[(size_t)node * NODEF + 128 + t] = f2b(fmaxf(a0 * inv, 0.f));
  if (t + 128 < DEMB) nodeFb[(size_t)node * NODEF + 128 + t + 128] = f2b(fmaxf(a1 * inv, 0.f));
}

// ---- gather pair rows: pairA[row][704] = [nodeFb[s](328), nodeFb[o](328), 0(48)] ----
__global__ __launch_bounds__(256)
void gather_kernel(const int* __restrict__ pidx, const unsigned short* __restrict__ nodeFb,
                   unsigned short* __restrict__ pairA) {
  const int lane = threadIdx.x & 63, wv = threadIdx.x >> 6;
  const int row = blockIdx.x * 4 + wv;        // wave per row
  const int b = row >> 12;
  const int s = pidx[2 * row], o = pidx[2 * row + 1];
  const uint4* ps = (const uint4*)(nodeFb + (size_t)((b << 7) + s) * NODEF);
  const uint4* po = (const uint4*)(nodeFb + (size_t)((b << 7) + o) * NODEF);
  uint4* dst = (uint4*)(pairA + (size_t)row * KGEOP);
  const uint4 z = make_uint4(0, 0, 0, 0);
  int c = lane;
  dst[c] = (c < 41) ? ps[c] : (c < 82) ? po[c - 41] : z;
  if (lane < 24) {
    c = lane + 64;
    dst[c] = (c < 82) ? po[c - 41] : z;
  }
}

// ---- relu + f32->bf16 cast (vectorized, grid-stride) ----
__global__ __launch_bounds__(256)
void relu_cast_kernel(const float* __restrict__ in, unsigned short* __restrict__ out, int n8) {
  for (int i = blockIdx.x * blockDim.x + threadIdx.x; i < n8; i += gridDim.x * blockDim.x) {
    float4 v0 = ((const float4*)in)[2 * i];
    float4 v1 = ((const float4*)in)[2 * i + 1];
    uint4 u;
    u.x = pack2(fmaxf(v0.x, 0.f), fmaxf(v0.y, 0.f));
    u.y = pack2(fmaxf(v0.z, 0.f), fmaxf(v0.w, 0.f));
    u.z = pack2(fmaxf(v1.x, 0.f), fmaxf(v1.y, 0.f));
    u.w = pack2(fmaxf(v1.z, 0.f), fmaxf(v1.w, 0.f));
    ((uint4*)out)[i] = u;
  }
}

// ---- fused LayerNorm + ReLU, in place, wave per row ----
template<int D>
__global__ __launch_bounds__(256)
void ln_relu_kernel(unsigned short* __restrict__ X,
                    const float* __restrict__ g, const float* __restrict__ bta) {
  constexpr int C = D / 64;                    // elems per lane (16 or 8)
  const int lane = threadIdx.x & 63, wv = threadIdx.x >> 6;
  const size_t row = (size_t)blockIdx.x * 4 + wv;
  unsigned short* xp = X + row * D + lane * C;
  float x[C];
#pragma unroll
  for (int c = 0; c < C; c += 8) {
    uint4 raw = *(const uint4*)(xp + c);
    unpack8(raw, x + c);
  }
  float s = 0.f, s2 = 0.f;
#pragma unroll
  for (int q = 0; q < C; q++) { s += x[q]; s2 = fmaf(x[q], x[q], s2); }
#pragma unroll
  for (int off = 32; off >= 1; off >>= 1) { s += __shfl_xor(s, off); s2 += __shfl_xor(s2, off); }
  const float mu = s / D;
  const float rs = rsqrtf(s2 / D - mu * mu + 1e-5f);
  const float* gp = g + lane * C;
  const float* bp = bta + lane * C;
#pragma unroll
  for (int c = 0; c < C; c += 8) {
    float4 g0 = *(const float4*)(gp + c), g1 = *(const float4*)(gp + c + 4);
    float4 t0 = *(const float4*)(bp + c), t1 = *(const float4*)(bp + c + 4);
    float y0 = fmaxf(fmaf((x[c + 0] - mu) * rs, g0.x, t0.x), 0.f);
    float y1 = fmaxf(fmaf((x[c + 1] - mu) * rs, g0.y, t0.y), 0.f);
    float y2 = fmaxf(fmaf((x[c + 2] - mu) * rs, g0.z, t0.z), 0.f);
    float y3 = fmaxf(fmaf((x[c + 3] - mu) * rs, g0.w, t0.w), 0.f);
    float y4 = fmaxf(fmaf((x[c + 4] - mu) * rs, g1.x, t1.x), 0.f);
    float y5 = fmaxf(fmaf((x[c + 5] - mu) * rs, g1.y, t1.y), 0.f);
    float y6 = fmaxf(fmaf((x[c + 6] - mu) * rs, g1.z, t1.z), 0.f);
    float y7 = fmaxf(fmaf((x[c + 7] - mu) * rs, g1.w, t1.w), 0.f);
    uint4 u;
    u.x = pack2(y0, y1); u.y = pack2(y2, y3);
    u.z = pack2(y4, y5); u.w = pack2(y6, y7);
    *(uint4*)(xp + c) = u;
  }
}

// ---- 256x256 deep-pipelined bf16 GEMM (T2 swizzle + counted vmcnt + setprio) ----
// 8 waves (2M x 4N), BK=64, LDS = 2 K-tile buffers of (A+B) = 128 KiB.
// Prefetch ledger: stage(0),stage(1) at prologue; stage(t+2) at end of iter t.
// Loop head waits vmcnt(8) (tile t done, tile t+1 in flight) EXCEPT the final
// iteration where only tile NT-1's 8 loads are outstanding -> must drain to 0
// (round-3 bug: vmcnt(8) was a no-op there -> MFMA read unstaged LDS).
__global__ __launch_bounds__(512)
void gemm256(const unsigned short* __restrict__ A, int ldaE,
             const unsigned short* __restrict__ Bt,
             const float* __restrict__ bias,
             unsigned short* __restrict__ C, int ldcE, int ccol0,
             int Ktot, int NBN) {
  __shared__ __align__(16) unsigned char smem[131072];
  const int tid = threadIdx.x;
  const int lane = tid & 63, w = tid >> 6;
  // bijective XCD swizzle (gridDim.x % 8 == 0)
  const int cpx = gridDim.x >> 3;
  const int swz = (blockIdx.x & 7) * cpx + (blockIdx.x >> 3);
  const int bm = swz / NBN, bn = swz - bm * NBN;

  // ---- staging geometry: 512 thr x 16B x 4 rounds per operand tile ----
  const int row0 = tid >> 3;                       // rows row0 + r*64
  const int dstCB = (tid & 7) * 16;                // linear dest col-byte
  const int srcCB = dstCB ^ ((row0 & 7) << 4);     // pre-swizzled source
  const size_t ldaBy = (size_t)ldaE * 2;
  const size_t ldbBy = (size_t)Ktot * 2;
  const unsigned char* aG = (const unsigned char*)A + (size_t)(bm * 256 + row0) * ldaBy + srcCB;
  const unsigned char* bG = (const unsigned char*)Bt + (size_t)(bn * 256 + row0) * ldbBy + srcCB;
  unsigned char* lA0 = smem + w * 1024;            // + buf*32768 + r*8192 (wave-uniform)
  unsigned char* lB0 = smem + 65536 + w * 1024;

  auto stage = [&](int buf, int kt) {
    const size_t ko = (size_t)kt * 128;
#pragma unroll
    for (int r = 0; r < 4; r++)
      async_copy16(aG + (size_t)r * 64 * ldaBy + ko, lA0 + buf * 32768 + r * 8192);
#pragma unroll
    for (int r = 0; r < 4; r++)
      async_copy16(bG + (size_t)r * 64 * ldbBy + ko, lB0 + buf * 32768 + r * 8192);
  };

  // ---- fragment read geometry ----
  const int wm = w >> 2, wn = w & 3;               // 2 x 4 waves
  const int frow = lane & 15;
  const int xorv = (lane & 7) << 4;
  const int kcb = (lane >> 4) * 16;
  const int c0 = kcb ^ xorv;                       // kk=0 col-byte (swizzled)
  const int c1 = (64 + kcb) ^ xorv;                // kk=1
  const int aRow0 = (wm * 128 + frow) * 128;       // byte offset of frag row base
  const int bRow0 = (wn * 64 + frow) * 128;

  f32x4 acc[8][4];
#pragma unroll
  for (int m = 0; m < 8; m++)
#pragma unroll
    for (int n = 0; n < 4; n++) acc[m][n] = (f32x4){0.f, 0.f, 0.f, 0.f};

  const int NT = Ktot >> 6;
  stage(0, 0);
  stage(1, 1);
  int cur = 0;
  for (int t = 0; t < NT; ++t) {
    if (t == NT - 1) asm volatile("s_waitcnt vmcnt(0)" ::: "memory");
    else             asm volatile("s_waitcnt vmcnt(8)" ::: "memory");
    __builtin_amdgcn_s_barrier();
    __builtin_amdgcn_sched_barrier(0);
    const unsigned char* ab = smem + cur * 32768;
    const unsigned char* bb = smem + 65536 + cur * 32768;
#pragma unroll
    for (int qm = 0; qm < 2; qm++) {
      bf16x8 af[4][2];
#pragma unroll
      for (int i = 0; i < 4; i++) {
        const int rb = aRow0 + (qm * 4 + i) * 2048;  // 16 rows * 128B
        af[i][0] = *(const bf16x8*)(ab + rb + c0);
        af[i][1] = *(const bf16x8*)(ab + rb + c1);
      }
#pragma unroll
      for (int qn = 0; qn < 2; qn++) {
        bf16x8 bfr[2][2];
#pragma unroll
        for (int j = 0; j < 2; j++) {
          const int rb = bRow0 + (qn * 2 + j) * 2048;
          bfr[j][0] = *(const bf16x8*)(bb + rb + c0);
          bfr[j][1] = *(const bf16x8*)(bb + rb + c1);
        }
        __builtin_amdgcn_s_setprio(1);
#pragma unroll
        for (int i = 0; i < 4; i++)
#pragma unroll
          for (int j = 0; j < 2; j++) {
            acc[qm * 4 + i][qn * 2 + j] =
              __builtin_amdgcn_mfma_f32_16x16x32_bf16(af[i][0], bfr[j][0],
                                                      acc[qm * 4 + i][qn * 2 + j], 0, 0, 0);
            acc[qm * 4 + i][qn * 2 + j] =
              __builtin_amdgcn_mfma_f32_16x16x32_bf16(af[i][1], bfr[j][1],
                                                      acc[qm * 4 + i][qn * 2 + j], 0, 0, 0);
          }
        __builtin_amdgcn_s_setprio(0);
      }
    }
    __builtin_amdgcn_sched_barrier(0);
    __builtin_amdgcn_s_barrier();
    __builtin_amdgcn_sched_barrier(0);
    if (t + 2 < NT) stage(cur, t + 2);
    cur ^= 1;
  }
  // ---- epilogue ----
  const int rb = bm * 256 + wm * 128 + ((lane >> 4) << 2);
  const int cb = bn * 256 + wn * 64 + frow;
#pragma unroll
  for (int n = 0; n < 4; n++) {
    const int col = cb + n * 16;
    const float bv = bias[col];
#pragma unroll
    for (int m = 0; m < 8; m++)
#pragma unroll
      for (int i = 0; i < 4; i++) {
        const int row = rb + m * 16 + i;
        C[(size_t)row * ldcE + ccol0 + col] = f2b(acc[m][n][i] + bv);
      }
  }
}

// ---- 128x128 m97-structure GEMM, kept for the cls layer (N=50) ----
__global__ __launch_bounds__(256)
void gemm_bf16(const unsigned short* __restrict__ A, int lda,
               const unsigned short* __restrict__ Bt,
               const float* __restrict__ bias,
               float* __restrict__ C,
               int Ktot, int NBN) {
  __shared__ unsigned short ldsA[128 * 64];
  __shared__ unsigned short ldsB[128 * 64];
  const int tid = threadIdx.x;
  const int lane = tid & 63, wid = tid >> 6;
  const int nwg = gridDim.x;
  const int cpx = nwg >> 3;
  const int swz = (blockIdx.x & 7) * cpx + (blockIdx.x >> 3);
  const int bm = swz / NBN, bn = swz - bm * NBN;

  const int srow = wid * 32 + (lane >> 3);
  const int skof = (lane & 7) * 8;
  const unsigned short* ag = A + (size_t)(bm * 128 + srow) * lda + skof;
  const unsigned short* bg = Bt + (size_t)(bn * 128 + srow) * Ktot + skof;

  f32x4 acc[4][4];
#pragma unroll
  for (int m = 0; m < 4; m++)
#pragma unroll
    for (int n = 0; n < 4; n++) acc[m][n] = (f32x4){0.f, 0.f, 0.f, 0.f};

  const int wm = wid >> 1, wn = wid & 1;
  const int frow = lane & 15;
  const int kgrp = (lane >> 4) << 3;

  for (int kt = 0; kt < Ktot; kt += 64) {
#pragma unroll
    for (int i = 0; i < 4; i++) {
      async_copy16(ag + (size_t)i * 8 * lda + kt, &ldsA[wid * 2048 + i * 512]);
      async_copy16(bg + (size_t)i * 8 * Ktot + kt, &ldsB[wid * 2048 + i * 512]);
    }
    __syncthreads();
#pragma unroll
    for (int kk = 0; kk < 64; kk += 32) {
      bf16x8 af[4], bfr[4];
#pragma unroll
      for (int m = 0; m < 4; m++)
        af[m] = *(const bf16x8*)&ldsA[(wm * 64 + m * 16 + frow) * 64 + kk + kgrp];
#pragma unroll
      for (int n = 0; n < 4; n++)
        bfr[n] = *(const bf16x8*)&ldsB[(wn * 64 + n * 16 + frow) * 64 + kk + kgrp];
#pragma unroll
      for (int m = 0; m < 4; m++)
#pragma unroll
        for (int n = 0; n < 4; n++)
          acc[m][n] = __builtin_amdgcn_mfma_f32_16x16x32_bf16(af[m], bfr[n], acc[m][n], 0, 0, 0);
    }
    __syncthreads();
  }
  const int rb = bm * 128 + wm * 64 + ((lane >> 4) << 2);
  const int cbl = wn * 64 + frow;
#pragma unroll
  for (int n = 0; n < 4; n++) {
    const int col = bn * 128 + cbl + n * 16;
    const float bv = (col < OUTC) ? bias[col] : 0.f;
#pragma unroll
    for (int m = 0; m < 4; m++)
#pragma unroll
      for (int i = 0; i < 4; i++) {
        const int row = rb + m * 16 + i;
        if (col < OUTC) C[(size_t)row * OUTC + col] = acc[m][n][i] + bv;
      }
  }
}

// ---- rowmax -> sigmoid -> last-wins scatter via atomicMax((p+1)<<32 | bits) ----
__global__ void score_kernel(const float* __restrict__ logits, const int* __restrict__ pidx,
                             unsigned long long* __restrict__ scat) {
  int row = blockIdx.x * blockDim.x + threadIdx.x;
  if (row >= M_) return;
  const float* lp = logits + (size_t)row * OUTC;
  float mx = lp[0];
#pragma unroll
  for (int j = 0; j < OUTC; j += 2) {
    float2 v = *(const float2*)(lp + j);
    mx = fmaxf(mx, fmaxf(v.x, v.y));
  }
  float sc = 1.f / (1.f + expf(-mx));
  int b = row >> 12, p = row & 4095;
  int s = pidx[2 * row], o = pidx[2 * row + 1];
  unsigned long long key = (((unsigned long long)(p + 1)) << 32) | (unsigned long long)__float_as_uint(sc);
  atomicMax(&scat[((size_t)(b * N_ + s) << 7) + o], key);
}

__global__ void relmat_kernel(const unsigned long long* __restrict__ scat, float* __restrict__ out) {
  int i = blockIdx.x * blockDim.x + threadIdx.x;
  if (i >= B_ * N_ * N_) return;
  unsigned long long v = scat[i];
  out[i] = v ? __uint_as_float((unsigned)(v & 0xffffffffu)) : 0.f;
}

extern "C" void kernel_launch(void* const* d_in, const int* in_sizes, int n_in,
                              void* d_out, int out_size, void* d_ws, size_t ws_size,
                              hipStream_t stream) {
  const float* visual_feat = (const float*)d_in[0];
  const float* box_info    = (const float*)d_in[1];
  const float* pred_logits = (const float*)d_in[2];
  const int*   pair_idx    = (const int*)d_in[3];
  const float* obj_sem_w   = (const float*)d_in[4];
  const float* pos_w1 = (const float*)d_in[5];
  const float* pos_b1 = (const float*)d_in[6];
  const float* pos_w2 = (const float*)d_in[7];
  const float* pos_b2 = (const float*)d_in[8];
  const float* vis_w  = (const float*)d_in[9];
  const float* vis_b  = (const float*)d_in[10];
  const float* geo_w  = (const float*)d_in[11];
  const float* geo_b  = (const float*)d_in[12];
  const float* fus_g  = (const float*)d_in[13];
  const float* fus_bt = (const float*)d_in[14];
  const float* fus_w  = (const float*)d_in[15];
  const float* fus_b  = (const float*)d_in[16];
  const float* cls_g  = (const float*)d_in[17];
  const float* cls_bt = (const float*)d_in[18];
  const float* cls_w  = (const float*)d_in[19];
  const float* cls_b  = (const float*)d_in[20];

  char* ws = (char*)d_ws;
  size_t off = 0;
  auto alloc = [&](size_t bytes) { char* p = ws + off; off += (bytes + 255) & ~(size_t)255; return p; };
  unsigned short* fused = (unsigned short*)alloc((size_t)M_ * 1024 * 2);      // 134 MB
  unsigned short* R1    = (unsigned short*)alloc((size_t)M_ * 1024 * 2);      // 134 MB: pairA -> visA -> fused2
  unsigned short* nodeFb = (unsigned short*)alloc((size_t)B_ * N_ * NODEF * 2);
  unsigned short* wT_vis = (unsigned short*)alloc((size_t)512 * 1024 * 2);
  unsigned short* wT_geo = (unsigned short*)alloc((size_t)512 * KGEOP * 2);
  unsigned short* wT_fus = (unsigned short*)alloc((size_t)512 * 1024 * 2);
  unsigned short* wT_cls = (unsigned short*)alloc((size_t)128 * 512 * 2);
  unsigned long long* scat = (unsigned long long*)alloc((size_t)B_ * N_ * N_ * 8);

  unsigned short* pairA  = R1;      // [M][704]
  unsigned short* visA   = R1;      // [M][1024] (after geo GEMM)
  unsigned short* fused2 = R1;      // [M][512]  (after vis GEMM)

  float* out_logits = (float*)d_out;
  float* out_rel = out_logits + (size_t)M_ * OUTC;

  zero_kernel<<<dim3(B_ * N_ * N_ * 8 / 4096), 256, 0, stream>>>((uint4*)scat);
  transpose_cvt<<<dim3((512 * 1024 + 255) / 256), 256, 0, stream>>>(vis_w, wT_vis, 1024, 512, 1024, 512);
  transpose_cvt<<<dim3((512 * KGEOP + 255) / 256), 256, 0, stream>>>(geo_w, wT_geo, KGEO, 512, KGEOP, 512);
  transpose_cvt<<<dim3((512 * 1024 + 255) / 256), 256, 0, stream>>>(fus_w, wT_fus, 1024, 512, 1024, 512);
  transpose_cvt<<<dim3((128 * 512 + 255) / 256), 256, 0, stream>>>(cls_w, wT_cls, 512, OUTC, 512, 128);
  node_kernel<<<dim3(B_ * N_), 128, 0, stream>>>(box_info, pred_logits, obj_sem_w,
                                                 pos_w1, pos_b1, pos_w2, pos_b2, nodeFb);
  gather_kernel<<<dim3(M_ / 4), 256, 0, stream>>>(pair_idx, nodeFb, pairA);
  gemm256<<<dim3(256 * 2), 512, 0, stream>>>(pairA, KGEOP, wT_geo, geo_b,
                                             fused, 1024, 512, KGEOP, 2);
  relu_cast_kernel<<<dim3(2048), 256, 0, stream>>>(visual_feat, visA, M_ * 1024 / 8);
  gemm256<<<dim3(256 * 2), 512, 0, stream>>>(visA, 1024, wT_vis, vis_b,
                                             fused, 1024, 0, 1024, 2);
  ln_relu_kernel<1024><<<dim3(M_ / 4), 256, 0, stream>>>(fused, fus_g, fus_bt);
  gemm256<<<dim3(256 * 2), 512, 0, stream>>>(fused, 1024, wT_fus, fus_b,
                                             fused2, 512, 0, 1024, 2);
  ln_relu_kernel<512><<<dim3(M_ / 4), 256, 0, stream>>>(fused2, cls_g, cls_bt);
  gemm_bf16<<<dim3(512), 256, 0, stream>>>(fused2, 512, wT_cls, cls_b,
                                           out_logits, 512, 1);
  score_kernel<<<dim3(M_ / 256), 256, 0, stream>>>(out_logits, pair_idx, scat);
  relmat_kernel<<<dim3((B_ * N_ * N_) / 256), 256, 0, stream>>>(scat, out_rel);
}

// Round 5
// 481.515 us; speedup vs baseline: 1.4284x; 1.0287x over previous
//
#include <hip/hip_runtime.h>
#include <cstdint>

#define B_    16
#define N_    128
#define P_    4096
#define M_    65536     // B_*P_
#define DIN   1024
#define DHID  512
#define DGEO  128
#define DEMB  200
#define NODEF 328       // DGEO + DEMB
#define NOBJ  151
#define OUTC  50
#define KGEO  656
#define KGEOP 672       // padded to multiple of 32 (ring-4 BK=32)

typedef __attribute__((ext_vector_type(8))) short bf16x8;
typedef __attribute__((ext_vector_type(4))) float f32x4;

typedef __attribute__((address_space(3))) unsigned char lds_u8;
typedef __attribute__((address_space(1))) unsigned char glb_u8;

static __device__ __forceinline__ void async_copy16(const void* g, void* l) {
  __builtin_amdgcn_global_load_lds((const glb_u8*)g, (lds_u8*)l, 16, 0, 0);
}

static __device__ __forceinline__ unsigned short f2b(float f) {
  union { float f; unsigned u; } v; v.f = f;
  unsigned r = v.u + 0x7fffu + ((v.u >> 16) & 1u);
  return (unsigned short)(r >> 16);
}
static __device__ __forceinline__ float b2f(unsigned short b) {
  union { unsigned u; float f; } v; v.u = ((unsigned)b) << 16;
  return v.f;
}
static __device__ __forceinline__ unsigned pack2(float a, float b) {
  return (unsigned)f2b(a) | ((unsigned)f2b(b) << 16);
}
static __device__ __forceinline__ void unpack8(uint4 raw, float* x) {
  x[0] = b2f(raw.x & 0xffffu); x[1] = b2f(raw.x >> 16);
  x[2] = b2f(raw.y & 0xffffu); x[3] = b2f(raw.y >> 16);
  x[4] = b2f(raw.z & 0xffffu); x[5] = b2f(raw.z >> 16);
  x[6] = b2f(raw.w & 0xffffu); x[7] = b2f(raw.w >> 16);
}

// ---- fast zero fill (also provides the zero-source region for geo gather) ----
__global__ __launch_bounds__(256)
void zero_kernel(uint4* __restrict__ p) {
  p[blockIdx.x * 256 + threadIdx.x] = make_uint4(0, 0, 0, 0);
}

// ---- weight transpose + bf16 cast: wT[n][k] = w[k][n], zero-padded ----
__global__ void transpose_cvt(const float* __restrict__ w, unsigned short* __restrict__ wT,
                              int K, int Nw, int Kpad, int Npad) {
  int idx = blockIdx.x * blockDim.x + threadIdx.x;
  if (idx >= Npad * Kpad) return;
  int n = idx / Kpad, k = idx - n * Kpad;
  float v = (n < Nw && k < K) ? w[(size_t)k * Nw + n] : 0.f;
  wT[idx] = f2b(v);
}

// ---- per-node features (relu'd, bf16): nodeFb[node] = [relu(pos)(128), relu(sem)(200)] ----
__global__ __launch_bounds__(128)
void node_kernel(const float* __restrict__ box, const float* __restrict__ plog,
                 const float* __restrict__ semw,
                 const float* __restrict__ w1, const float* __restrict__ b1,
                 const float* __restrict__ w2, const float* __restrict__ b2,
                 unsigned short* __restrict__ nodeFb) {
  const int node = blockIdx.x;          // 0..2047
  const int t = threadIdx.x;            // 0..127 (2 waves)
  __shared__ float sBox[9];
  __shared__ float sH[128];
  __shared__ float sE[NOBJ];
  __shared__ float sRed[4];
  if (t < 9) sBox[t] = box[node * 9 + t];
  float l0 = (t < NOBJ) ? plog[node * NOBJ + t] : -1e30f;
  float l1 = (t + 128 < NOBJ) ? plog[node * NOBJ + t + 128] : -1e30f;
  __syncthreads();
  float h = b1[t];
#pragma unroll
  for (int i = 0; i < 9; i++) h = fmaf(sBox[i], w1[i * 128 + t], h);
  h = fmaxf(h, 0.f);
  sH[t] = h;
  float mx = fmaxf(l0, l1);
#pragma unroll
  for (int off = 32; off >= 1; off >>= 1) mx = fmaxf(mx, __shfl_xor(mx, off));
  if ((t & 63) == 0) sRed[t >> 6] = mx;
  __syncthreads();
  mx = fmaxf(sRed[0], sRed[1]);
  float e0 = (t < NOBJ) ? expf(l0 - mx) : 0.f;
  float e1 = (t + 128 < NOBJ) ? expf(l1 - mx) : 0.f;
  if (t < NOBJ) sE[t] = e0;
  if (t + 128 < NOBJ) sE[t + 128] = e1;
  float sm = e0 + e1;
#pragma unroll
  for (int off = 32; off >= 1; off >>= 1) sm += __shfl_xor(sm, off);
  if ((t & 63) == 0) sRed[2 + (t >> 6)] = sm;
  __syncthreads();
  const float inv = 1.f / (sRed[2] + sRed[3]);
  float pv = b2[t];
  for (int i = 0; i < 128; i++) pv = fmaf(sH[i], w2[i * 128 + t], pv);
  nodeFb[(size_t)node * NODEF + t] = f2b(fmaxf(pv, 0.f));
  float a0 = 0.f, a1 = 0.f;
  const int d1 = (t + 128 < DEMB) ? (t + 128) : 0;
  for (int i = 0; i < NOBJ; i++) {
    float e = sE[i];
    a0 = fmaf(e, semw[i * DEMB + t], a0);
    a1 = fmaf(e, semw[i * DEMB + d1], a1);
  }
  nodeFb[(size_t)node * NODEF + 128 + t] = f2b(fmaxf(a0 * inv, 0.f));
  if (t + 128 < DEMB) nodeFb[(size_t)node * NODEF + 128 + t + 128] = f2b(fmaxf(a1 * inv, 0.f));
}

// ---- relu + f32->bf16 cast (vectorized, grid-stride) ----
__global__ __launch_bounds__(256)
void relu_cast_kernel(const float* __restrict__ in, unsigned short* __restrict__ out, int n8) {
  for (int i = blockIdx.x * blockDim.x + threadIdx.x; i < n8; i += gridDim.x * blockDim.x) {
    float4 v0 = ((const float4*)in)[2 * i];
    float4 v1 = ((const float4*)in)[2 * i + 1];
    uint4 u;
    u.x = pack2(fmaxf(v0.x, 0.f), fmaxf(v0.y, 0.f));
    u.y = pack2(fmaxf(v0.z, 0.f), fmaxf(v0.w, 0.f));
    u.z = pack2(fmaxf(v1.x, 0.f), fmaxf(v1.y, 0.f));
    u.w = pack2(fmaxf(v1.z, 0.f), fmaxf(v1.w, 0.f));
    ((uint4*)out)[i] = u;
  }
}

// ---- fused LayerNorm + ReLU, in place, wave per row ----
template<int D>
__global__ __launch_bounds__(256)
void ln_relu_kernel(unsigned short* __restrict__ X,
                    const float* __restrict__ g, const float* __restrict__ bta) {
  constexpr int C = D / 64;                    // elems per lane (16 or 8)
  const int lane = threadIdx.x & 63, wv = threadIdx.x >> 6;
  const size_t row = (size_t)blockIdx.x * 4 + wv;
  unsigned short* xp = X + row * D + lane * C;
  float x[C];
#pragma unroll
  for (int c = 0; c < C; c += 8) {
    uint4 raw = *(const uint4*)(xp + c);
    unpack8(raw, x + c);
  }
  float s = 0.f, s2 = 0.f;
#pragma unroll
  for (int q = 0; q < C; q++) { s += x[q]; s2 = fmaf(x[q], x[q], s2); }
#pragma unroll
  for (int off = 32; off >= 1; off >>= 1) { s += __shfl_xor(s, off); s2 += __shfl_xor(s2, off); }
  const float mu = s / D;
  const float rs = rsqrtf(s2 / D - mu * mu + 1e-5f);
  const float* gp = g + lane * C;
  const float* bp = bta + lane * C;
#pragma unroll
  for (int c = 0; c < C; c += 8) {
    float4 g0 = *(const float4*)(gp + c), g1 = *(const float4*)(gp + c + 4);
    float4 t0 = *(const float4*)(bp + c), t1 = *(const float4*)(bp + c + 4);
    float y0 = fmaxf(fmaf((x[c + 0] - mu) * rs, g0.x, t0.x), 0.f);
    float y1 = fmaxf(fmaf((x[c + 1] - mu) * rs, g0.y, t0.y), 0.f);
    float y2 = fmaxf(fmaf((x[c + 2] - mu) * rs, g0.z, t0.z), 0.f);
    float y3 = fmaxf(fmaf((x[c + 3] - mu) * rs, g0.w, t0.w), 0.f);
    float y4 = fmaxf(fmaf((x[c + 4] - mu) * rs, g1.x, t1.x), 0.f);
    float y5 = fmaxf(fmaf((x[c + 5] - mu) * rs, g1.y, t1.y), 0.f);
    float y6 = fmaxf(fmaf((x[c + 6] - mu) * rs, g1.z, t1.z), 0.f);
    float y7 = fmaxf(fmaf((x[c + 7] - mu) * rs, g1.w, t1.w), 0.f);
    uint4 u;
    u.x = pack2(y0, y1); u.y = pack2(y2, y3);
    u.z = pack2(y4, y5); u.w = pack2(y6, y7);
    *(uint4*)(xp + c) = u;
  }
}

// ---- 256x256 ring-4 pipelined bf16 GEMM, BK=32, distance-3 prefetch ----
// Ledger: prologue stages steps 0,1,2 (4 loads each). Phase s: vmcnt(8) drains
// step s ({s,s+1,s+2}=12 outstanding); tail s=NS-2 -> vmcnt(4), s=NS-1 -> vmcnt(0).
// One barrier per phase. stage(s+3) overwrites slot (s-1)&3 whose readers all
// passed this phase's barrier. LDS swizzle: slot16 ^= (row>>1)&3, write-side
// applied on the pre-swizzled GLOBAL source (rule #21).
// MODE 0: A = plain bf16 [M][ldaE].  MODE 1: A = gathered pair rows from nodeFb
// (subj 0..327 | obj 328..655 | zero 656..671) via per-lane gload_lds source.
template<int MODE>
__global__ __launch_bounds__(512)
void gemm256r(const unsigned short* __restrict__ A, int ldaE,
              const unsigned short* __restrict__ Bt, int ldbE,
              const float* __restrict__ bias,
              unsigned short* __restrict__ C, int ldcE, int ccol0,
              int NS, int NBN,
              const int* __restrict__ pidx,
              const unsigned short* __restrict__ nodeFb,
              const unsigned short* __restrict__ zsrc) {
  __shared__ __align__(16) unsigned char smem[131072];   // A: 4x16K, B: 4x16K @64K
  const int tid = threadIdx.x;
  const int lane = tid & 63, w = tid >> 6;
  const int cpx = gridDim.x >> 3;                        // bijective XCD swizzle
  const int swz = (blockIdx.x & 7) * cpx + (blockIdx.x >> 3);
  const int bm = swz / NBN, bn = swz - bm * NBN;

  // staging: load r in {0,1}: dest = slot*16384 + r*8192 + w*1024 (+lane*16 by HW)
  // dest row = r*128 + (tid>>2), dest slot16 = tid&3; source slot16 pre-swizzled:
  const int sslot = (tid & 3) ^ ((tid >> 3) & 3);
  const int srow = tid >> 2;
  const size_t ldaBy = (size_t)ldaE * 2, ldbBy = (size_t)ldbE * 2;
  const unsigned char* aG = (const unsigned char*)A + (size_t)(bm * 256 + srow) * ldaBy + sslot * 16;
  const unsigned char* bG = (const unsigned char*)Bt + (size_t)(bn * 256 + srow) * ldbBy + sslot * 16;

  const unsigned short* nbS[2];
  const unsigned short* nbO[2];
  if (MODE == 1) {
#pragma unroll
    for (int r = 0; r < 2; r++) {
      int pr = bm * 256 + r * 128 + srow;
      int2 so = *(const int2*)(pidx + 2 * pr);
      int b = pr >> 12;
      nbS[r] = nodeFb + (size_t)((b << 7) + so.x) * NODEF;
      nbO[r] = nodeFb + (size_t)((b << 7) + so.y) * NODEF;
    }
  }

  auto stage = [&](int s) {
    const int slot = s & 3;
    unsigned char* la = smem + slot * 16384 + w * 1024;
    unsigned char* lb = smem + 65536 + slot * 16384 + w * 1024;
    if (MODE == 0) {
      const unsigned char* sa = aG + (size_t)s * 64;
      async_copy16(sa, la);
      async_copy16(sa + 128 * ldaBy, la + 8192);
    } else {
      const int e = s * 32 + sslot * 8;     // k-elem offset of this thread's 16B
#pragma unroll
      for (int r = 0; r < 2; r++) {
        uintptr_t ps = (uintptr_t)(nbS[r] + e);
        uintptr_t po = (uintptr_t)(nbO[r] + (e - NODEF));
        uintptr_t pz = (uintptr_t)zsrc;
        uintptr_t sel = (e < NODEF) ? ps : ((e < KGEO) ? po : pz);
        async_copy16((const void*)sel, la + r * 8192);
      }
    }
    const unsigned char* sb = bG + (size_t)s * 64;
    async_copy16(sb, lb);
    async_copy16(sb + 128 * ldbBy, lb + 8192);
  };

  // fragment geometry: rows of 64B; read col = (g ^ ((frow>>1)&3))*16
  const int wm = w >> 2, wn = w & 3;                 // 2M x 4N waves
  const int frow = lane & 15;
  const int colb = (((lane >> 4) ^ ((frow >> 1) & 3)) << 4);
  const int aRowB = (wm * 128 + frow) * 64;
  const int bRowB = (wn * 64 + frow) * 64;

  f32x4 acc[8][4];
#pragma unroll
  for (int m = 0; m < 8; m++)
#pragma unroll
    for (int n = 0; n < 4; n++) acc[m][n] = (f32x4){0.f, 0.f, 0.f, 0.f};

  stage(0); stage(1); stage(2);
  for (int s = 0; s < NS; ++s) {
    if (s == NS - 1)      asm volatile("s_waitcnt vmcnt(0)" ::: "memory");
    else if (s == NS - 2) asm volatile("s_waitcnt vmcnt(4)" ::: "memory");
    else                  asm volatile("s_waitcnt vmcnt(8)" ::: "memory");
    __builtin_amdgcn_s_barrier();
    __builtin_amdgcn_sched_barrier(0);
    if (s + 3 < NS) stage(s + 3);
    const unsigned char* ab = smem + (s & 3) * 16384;
    const unsigned char* bb = smem + 65536 + (s & 3) * 16384;
    bf16x8 af[8], bfv[4];
#pragma unroll
    for (int m = 0; m < 8; m++) af[m] = *(const bf16x8*)(ab + aRowB + m * 1024 + colb);
#pragma unroll
    for (int n = 0; n < 4; n++) bfv[n] = *(const bf16x8*)(bb + bRowB + n * 1024 + colb);
    __builtin_amdgcn_s_setprio(1);
#pragma unroll
    for (int m = 0; m < 8; m++)
#pragma unroll
      for (int n = 0; n < 4; n++)
        acc[m][n] = __builtin_amdgcn_mfma_f32_16x16x32_bf16(af[m], bfv[n], acc[m][n], 0, 0, 0);
    __builtin_amdgcn_s_setprio(0);
    __builtin_amdgcn_sched_barrier(0);
  }
  // epilogue
  const int rb = bm * 256 + wm * 128 + ((lane >> 4) << 2);
  const int cb = bn * 256 + wn * 64 + frow;
#pragma unroll
  for (int n = 0; n < 4; n++) {
    const int col = cb + n * 16;
    const float bv = bias[col];
#pragma unroll
    for (int m = 0; m < 8; m++)
#pragma unroll
      for (int i = 0; i < 4; i++) {
        const int row = rb + m * 16 + i;
        C[(size_t)row * ldcE + ccol0 + col] = f2b(acc[m][n][i] + bv);
      }
  }
}

// ---- 128x128 m97-structure GEMM for cls layer (N=50) + fused score scatter ----
__global__ __launch_bounds__(256)
void gemm_cls(const unsigned short* __restrict__ A, int lda,
              const unsigned short* __restrict__ Bt,
              const float* __restrict__ bias,
              float* __restrict__ C,
              int Ktot,
              const int* __restrict__ pidx,
              unsigned long long* __restrict__ scat) {
  __shared__ unsigned short ldsA[128 * 64];
  __shared__ unsigned short ldsB[128 * 64];
  const int tid = threadIdx.x;
  const int lane = tid & 63, wid = tid >> 6;
  const int cpx = gridDim.x >> 3;
  const int bm = (blockIdx.x & 7) * cpx + (blockIdx.x >> 3);

  const int srow = wid * 32 + (lane >> 3);
  const int skof = (lane & 7) * 8;
  const unsigned short* ag = A + (size_t)(bm * 128 + srow) * lda + skof;
  const unsigned short* bg = Bt + (size_t)srow * Ktot + skof;

  f32x4 acc[4][4];
#pragma unroll
  for (int m = 0; m < 4; m++)
#pragma unroll
    for (int n = 0; n < 4; n++) acc[m][n] = (f32x4){0.f, 0.f, 0.f, 0.f};

  const int wm = wid >> 1, wn = wid & 1;
  const int frow = lane & 15;
  const int kgrp = (lane >> 4) << 3;

  for (int kt = 0; kt < Ktot; kt += 64) {
#pragma unroll
    for (int i = 0; i < 4; i++) {
      async_copy16(ag + (size_t)i * 8 * lda + kt, &ldsA[wid * 2048 + i * 512]);
      async_copy16(bg + (size_t)i * 8 * Ktot + kt, &ldsB[wid * 2048 + i * 512]);
    }
    __syncthreads();
#pragma unroll
    for (int kk = 0; kk < 64; kk += 32) {
      bf16x8 af[4], bfr[4];
#pragma unroll
      for (int m = 0; m < 4; m++)
        af[m] = *(const bf16x8*)&ldsA[(wm * 64 + m * 16 + frow) * 64 + kk + kgrp];
#pragma unroll
      for (int n = 0; n < 4; n++)
        bfr[n] = *(const bf16x8*)&ldsB[(wn * 64 + n * 16 + frow) * 64 + kk + kgrp];
#pragma unroll
      for (int m = 0; m < 4; m++)
#pragma unroll
        for (int n = 0; n < 4; n++)
          acc[m][n] = __builtin_amdgcn_mfma_f32_16x16x32_bf16(af[m], bfr[n], acc[m][n], 0, 0, 0);
    }
    __syncthreads();
  }
  const int rb = bm * 128 + wm * 64 + ((lane >> 4) << 2);
#pragma unroll
  for (int n = 0; n < 4; n++) {
    const int col = wn * 64 + frow + n * 16;
    const float bv = (col < OUTC) ? bias[col] : 0.f;
#pragma unroll
    for (int m = 0; m < 4; m++)
#pragma unroll
      for (int i = 0; i < 4; i++) {
        const int row = rb + m * 16 + i;
        if (col < OUTC) C[(size_t)row * OUTC + col] = acc[m][n][i] + bv;
      }
  }
  // fused score: wn==0 waves hold cols 0..63 of their 64 rows
  if (wn == 0) {
#pragma unroll
    for (int m = 0; m < 4; m++)
#pragma unroll
      for (int i = 0; i < 4; i++) {
        float mx = -1e30f;
#pragma unroll
        for (int n = 0; n < 4; n++) {
          const int col = n * 16 + frow;
          float v = acc[m][n][i] + ((col < OUTC) ? bias[col] : 0.f);
          if (col < OUTC) mx = fmaxf(mx, v);
        }
        mx = fmaxf(mx, __shfl_xor(mx, 1));
        mx = fmaxf(mx, __shfl_xor(mx, 2));
        mx = fmaxf(mx, __shfl_xor(mx, 4));
        mx = fmaxf(mx, __shfl_xor(mx, 8));
        if (frow == 0) {
          const int row = rb + m * 16 + i;
          float sc = 1.f / (1.f + expf(-mx));
          int b = row >> 12, p = row & 4095;
          int s = pidx[2 * row], o = pidx[2 * row + 1];
          unsigned long long key = (((unsigned long long)(p + 1)) << 32) |
                                   (unsigned long long)__float_as_uint(sc);
          atomicMax(&scat[((size_t)(b * N_ + s) << 7) + o], key);
        }
      }
  }
}

__global__ void relmat_kernel(const unsigned long long* __restrict__ scat, float* __restrict__ out) {
  int i = blockIdx.x * blockDim.x + threadIdx.x;
  if (i >= B_ * N_ * N_) return;
  unsigned long long v = scat[i];
  out[i] = v ? __uint_as_float((unsigned)(v & 0xffffffffu)) : 0.f;
}

extern "C" void kernel_launch(void* const* d_in, const int* in_sizes, int n_in,
                              void* d_out, int out_size, void* d_ws, size_t ws_size,
                              hipStream_t stream) {
  const float* visual_feat = (const float*)d_in[0];
  const float* box_info    = (const float*)d_in[1];
  const float* pred_logits = (const float*)d_in[2];
  const int*   pair_idx    = (const int*)d_in[3];
  const float* obj_sem_w   = (const float*)d_in[4];
  const float* pos_w1 = (const float*)d_in[5];
  const float* pos_b1 = (const float*)d_in[6];
  const float* pos_w2 = (const float*)d_in[7];
  const float* pos_b2 = (const float*)d_in[8];
  const float* vis_w  = (const float*)d_in[9];
  const float* vis_b  = (const float*)d_in[10];
  const float* geo_w  = (const float*)d_in[11];
  const float* geo_b  = (const float*)d_in[12];
  const float* fus_g  = (const float*)d_in[13];
  const float* fus_bt = (const float*)d_in[14];
  const float* fus_w  = (const float*)d_in[15];
  const float* fus_b  = (const float*)d_in[16];
  const float* cls_g  = (const float*)d_in[17];
  const float* cls_bt = (const float*)d_in[18];
  const float* cls_w  = (const float*)d_in[19];
  const float* cls_b  = (const float*)d_in[20];

  char* ws = (char*)d_ws;
  size_t off = 0;
  auto alloc = [&](size_t bytes) { char* p = ws + off; off += (bytes + 255) & ~(size_t)255; return p; };
  unsigned short* fused = (unsigned short*)alloc((size_t)M_ * 1024 * 2);      // 134 MB
  unsigned short* R1    = (unsigned short*)alloc((size_t)M_ * 1024 * 2);      // 134 MB: visA -> fused2
  unsigned short* nodeFb = (unsigned short*)alloc((size_t)B_ * N_ * NODEF * 2);
  unsigned short* wT_vis = (unsigned short*)alloc((size_t)512 * 1024 * 2);
  unsigned short* wT_geo = (unsigned short*)alloc((size_t)512 * KGEOP * 2);
  unsigned short* wT_fus = (unsigned short*)alloc((size_t)512 * 1024 * 2);
  unsigned short* wT_cls = (unsigned short*)alloc((size_t)128 * 512 * 2);
  unsigned long long* scat = (unsigned long long*)alloc((size_t)B_ * N_ * N_ * 8);

  unsigned short* visA   = R1;      // [M][1024]
  unsigned short* fused2 = R1;      // [M][512]  (after vis GEMM consumed visA)

  float* out_logits = (float*)d_out;
  float* out_rel = out_logits + (size_t)M_ * OUTC;

  // scat zeroed first: doubles as the zero-source for geo gather staging
  zero_kernel<<<dim3(B_ * N_ * N_ * 8 / 4096), 256, 0, stream>>>((uint4*)scat);
  transpose_cvt<<<dim3((512 * 1024 + 255) / 256), 256, 0, stream>>>(vis_w, wT_vis, 1024, 512, 1024, 512);
  transpose_cvt<<<dim3((512 * KGEOP + 255) / 256), 256, 0, stream>>>(geo_w, wT_geo, KGEO, 512, KGEOP, 512);
  transpose_cvt<<<dim3((512 * 1024 + 255) / 256), 256, 0, stream>>>(fus_w, wT_fus, 1024, 512, 1024, 512);
  transpose_cvt<<<dim3((128 * 512 + 255) / 256), 256, 0, stream>>>(cls_w, wT_cls, 512, OUTC, 512, 128);
  node_kernel<<<dim3(B_ * N_), 128, 0, stream>>>(box_info, pred_logits, obj_sem_w,
                                                 pos_w1, pos_b1, pos_w2, pos_b2, nodeFb);
  // geo GEMM with fused pair-gather (A from nodeFb via per-lane gload_lds src)
  gemm256r<1><<<dim3(256 * 2), 512, 0, stream>>>(nullptr, 0, wT_geo, KGEOP, geo_b,
                                                 fused, 1024, 512, KGEOP / 32, 2,
                                                 pair_idx, nodeFb, (const unsigned short*)scat);
  relu_cast_kernel<<<dim3(2048), 256, 0, stream>>>(visual_feat, visA, M_ * 1024 / 8);
  gemm256r<0><<<dim3(256 * 2), 512, 0, stream>>>(visA, 1024, wT_vis, 1024, vis_b,
                                                 fused, 1024, 0, 1024 / 32, 2,
                                                 nullptr, nullptr, nullptr);
  ln_relu_kernel<1024><<<dim3(M_ / 4), 256, 0, stream>>>(fused, fus_g, fus_bt);
  gemm256r<0><<<dim3(256 * 2), 512, 0, stream>>>(fused, 1024, wT_fus, 1024, fus_b,
                                                 fused2, 512, 0, 1024 / 32, 2,
                                                 nullptr, nullptr, nullptr);
  ln_relu_kernel<512><<<dim3(M_ / 4), 256, 0, stream>>>(fused2, cls_g, cls_bt);
  gemm_cls<<<dim3(512), 256, 0, stream>>>(fused2, 512, wT_cls, cls_b,
                                          out_logits, 512, pair_idx, scat);
  relmat_kernel<<<dim3((B_ * N_ * N_) / 256), 256, 0, stream>>>(scat, out_rel);
}